// Round 8
// baseline (382.146 us; speedup 1.0000x reference)
//
#include <hip/hip_runtime.h>
#include <hip/hip_bf16.h>

// MultiHeadAttention: N=2048, H=16, D=128. f32 in, f32 out, int32 mask.
// R7->R8: fix compile error only — __exp2f is not a HIP device function;
// use __builtin_amdgcn_exp2f (v_exp_f32 = 2^x). Design unchanged from R7:
// BARRIER-FREE attn: both B-operands (qp tile, vpT tile) consumed in exact
// B-frag layout -> load straight global->VGPR (16B, lane-contiguous); L1
// dedups 4-wave reuse. Only Pb (P C->A layout transform) in per-wave LDS
// (lgkmcnt-ordered, no s_barrier). Zero __syncthreads in the j-loop =>
// 8 waves/CU self-pipeline via vmcnt. Grid head-major for XCD L2 locality.

#define HN 16
#define NN 2048
#define DD 128

typedef __attribute__((ext_vector_type(8))) short short8;   // MFMA A/B frag
typedef __attribute__((ext_vector_type(4))) short short4v;
typedef __attribute__((ext_vector_type(4))) float float4v;  // MFMA C/D frag

__device__ inline unsigned short f2bf(float f) {
    unsigned int u = __builtin_bit_cast(unsigned int, f);
    unsigned int r = (u + 0x7fffu + ((u >> 16) & 1u)) >> 16;  // RNE
    return (unsigned short)r;
}

// 8 contiguous f32 -> bf16 MFMA frag
__device__ inline short8 ld_bf8(const float* __restrict__ p) {
    const float4v a = *(const float4v*)p;
    const float4v b = *(const float4v*)(p + 4);
    short8 r;
    r[0] = (short)f2bf(a[0]); r[1] = (short)f2bf(a[1]);
    r[2] = (short)f2bf(a[2]); r[3] = (short)f2bf(a[3]);
    r[4] = (short)f2bf(b[0]); r[5] = (short)f2bf(b[1]);
    r[6] = (short)f2bf(b[2]); r[7] = (short)f2bf(b[3]);
    return r;
}

// two ds_read_b64 frag load (for odd-pitch LDS arrays; needs 8B align)
__device__ inline short8 ld2x4(const unsigned short* p) {
    const short4v lo = *(const short4v*)p;
    const short4v hi = *(const short4v*)(p + 4);
    short8 r;
    r[0] = lo[0]; r[1] = lo[1]; r[2] = lo[2]; r[3] = lo[3];
    r[4] = hi[0]; r[5] = hi[1]; r[6] = hi[2]; r[7] = hi[3];
    return r;
}

__global__ void sentinel_kernel(float* out, int n) {
    int i = blockIdx.x * 256 + threadIdx.x;
    if (i < n) out[i] = 2.0f;
}

// ---------------------------------------------------------------------------
// Kernel A: projections. grid = (32 row-tiles, 16 heads, 3 tensors).
// t<2: qp/kp row-major [n][d].  t==2: vpT [d][n] via operand swap.
// ---------------------------------------------------------------------------
__global__ __launch_bounds__(256) void proj_kernel(
    const float* __restrict__ q,
    const float* __restrict__ k,
    const float* __restrict__ v,
    const float* __restrict__ Qw,
    const float* __restrict__ Kw,
    const float* __restrict__ Vw,
    unsigned short* __restrict__ ws)
{
    __shared__ __align__(16) unsigned short Wt[128 * 132];  // Wt[e][d] = bf16(W[d][e])
    const int t = blockIdx.z, h = blockIdx.y, rb = blockIdx.x;
    const int tid = threadIdx.x;
    const float* in = (t == 0) ? q : ((t == 1) ? k : v);
    const float* W  = ((t == 0) ? Qw : ((t == 1) ? Kw : Vw)) + h * DD * DD;
    unsigned short* out = ws + (size_t)t * (HN * NN * DD) + (size_t)h * (NN * DD);

    for (int idx2 = tid * 2; idx2 < DD * DD; idx2 += 512) {
        const int d = idx2 >> 7, e = idx2 & 127;
        const float2 w2 = *(const float2*)(W + idx2);
        Wt[(e + 0) * 132 + d] = f2bf(w2.x);
        Wt[(e + 1) * 132 + d] = f2bf(w2.y);
    }
    __syncthreads();

    const int wave = tid >> 6, lane = tid & 63;
    const int quad = lane >> 4, l16 = lane & 15;
    const int row0 = rb * 64 + wave * 16;   // token tile base for this wave

    float4v acc[8];
    for (int c = 0; c < 8; c++) acc[c] = {0.f, 0.f, 0.f, 0.f};

    if (t < 2) {
        for (int kk = 0; kk < 4; kk++) {
            const short8 a = ld_bf8(in + (size_t)(row0 + l16) * DD + kk * 32 + quad * 8);
            for (int c = 0; c < 8; c++) {
                const short8 b = ld2x4(&Wt[(c * 16 + l16) * 132 + kk * 32 + quad * 8]);
                acc[c] = __builtin_amdgcn_mfma_f32_16x16x32_bf16(a, b, acc[c], 0, 0, 0);
            }
        }
        for (int c = 0; c < 8; c++)
            for (int r = 0; r < 4; r++)
                out[(size_t)(row0 + quad * 4 + r) * DD + c * 16 + l16] = f2bf(acc[c][r]);
    } else {
        // D[e][token] = vpT: A = Wt rows (Wv^T), B = v rows
        for (int kk = 0; kk < 4; kk++) {
            const short8 bv = ld_bf8(in + (size_t)(row0 + l16) * DD + kk * 32 + quad * 8);
            for (int c = 0; c < 8; c++) {
                const short8 aw = ld2x4(&Wt[(c * 16 + l16) * 132 + kk * 32 + quad * 8]);
                acc[c] = __builtin_amdgcn_mfma_f32_16x16x32_bf16(aw, bv, acc[c], 0, 0, 0);
            }
        }
        for (int c = 0; c < 8; c++)
            for (int r = 0; r < 4; r++)
                out[(size_t)(c * 16 + quad * 4 + r) * NN + row0 + l16] = f2bf(acc[c][r]);
    }
}

// ---------------------------------------------------------------------------
// Kernel B: barrier-free flash attention. grid = (16 heads, 32 i-tiles).
// All MFMA operands loaded global->VGPR in fragment layout; only the P
// layout transform round-trips through per-wave LDS (lgkmcnt-ordered).
// ---------------------------------------------------------------------------
__global__ __launch_bounds__(256) void attn_kernel(
    unsigned short* __restrict__ ws,
    const int* __restrict__ mask)
{
    __shared__ __align__(16) unsigned short Pb[4 * 16 * 72];  // per-wave P (16x64)

    const int h = blockIdx.x, ib = blockIdx.y;   // head-major for XCD locality
    const int tid = threadIdx.x;
    const int wave = tid >> 6, lane = tid & 63;
    const int quad = lane >> 4, l16 = lane & 15;

    const unsigned short* qp  = ws + (size_t)h * (NN * DD);
    const unsigned short* kp  = ws + (size_t)(HN * NN * DD) + (size_t)h * (NN * DD);
    const unsigned short* vpT = ws + (size_t)(2 * HN * NN * DD) + (size_t)h * (NN * DD);
    unsigned short* ao = ws + (size_t)(3 * HN * NN * DD);  // [N][H*D]

    const int i0 = ib * 64;
    // exp(s*scale - 5) = exp2(s*c1 + c2)
    const float c1 = 0.022097086912079612f * 1.44269504088896f;
    const float c2 = -5.0f * 1.44269504088896f;

    short8 ones;
    for (int i = 0; i < 8; i++) ones[i] = (short)0x3F80;  // bf16 1.0

    // Preload kp A-fragments (16 i-rows, reused all j-iters)
    short8 afragK[4];
    {
        const int row = i0 + wave * 16 + l16;
        for (int kk = 0; kk < 4; kk++)
            afragK[kk] = *(const short8*)(kp + (size_t)row * DD + kk * 32 + quad * 8);
    }

    unsigned short* PbW = &Pb[wave * 16 * 72];
    const int gi_base = i0 + wave * 16 + quad * 4;

    float4v o[8];
    for (int c = 0; c < 8; c++) o[c] = {0.f, 0.f, 0.f, 0.f};
    float4v lacc = {0.f, 0.f, 0.f, 0.f};

    for (int j0 = 0; j0 < NN; j0 += 64) {
        // S = kp_tile · qp_tile^T  — B-frags straight from global
        float4v s[4];
        for (int c = 0; c < 4; c++) s[c] = {0.f, 0.f, 0.f, 0.f};
        for (int kk = 0; kk < 4; kk++) {
            for (int c = 0; c < 4; c++) {
                const short8 b = *(const short8*)(qp + (size_t)(j0 + c * 16 + l16) * DD + kk * 32 + quad * 8);
                s[c] = __builtin_amdgcn_mfma_f32_16x16x32_bf16(afragK[kk], b, s[c], 0, 0, 0);
            }
        }

        // static-max softmax: p = exp2(s*c1 + c2); masked -> ~0
        for (int r = 0; r < 4; r++) {
            const int gi = gi_base + r;
            for (int c = 0; c < 4; c++) {
                const int mv = mask[(size_t)gi * NN + j0 + c * 16 + l16];
                const float x = mv ? fmaf(s[c][r], c1, c2) : -72.0f;
                PbW[(quad * 4 + r) * 72 + c * 16 + l16] = f2bf(__builtin_amdgcn_exp2f(x));
            }
        }
        // per-wave LDS RAW: ordered by lgkmcnt, no barrier.

        // O += P · vp_tile ; l += P · ones  — vpT B-frags straight from global
        for (int ks = 0; ks < 2; ks++) {
            const short8 ap = *(const short8*)(&PbW[l16 * 72 + ks * 32 + quad * 8]);
            for (int dc = 0; dc < 8; dc++) {
                const short8 bv = *(const short8*)(vpT + (size_t)(dc * 16 + l16) * NN + j0 + ks * 32 + quad * 8);
                o[dc] = __builtin_amdgcn_mfma_f32_16x16x32_bf16(ap, bv, o[dc], 0, 0, 0);
            }
            lacc = __builtin_amdgcn_mfma_f32_16x16x32_bf16(ap, ones, lacc, 0, 0, 0);
        }
    }

    // epilogue: normalize, store [i][h*128+d]
    for (int r = 0; r < 4; r++) {
        const float inv = (lacc[r] > 0.f) ? (1.0f / lacc[r]) : 0.f;
        const int gi = gi_base + r;
        for (int dc = 0; dc < 8; dc++)
            ao[(size_t)gi * (HN * DD) + h * DD + dc * 16 + l16] = f2bf(o[dc][r] * inv);
    }
}

// ---------------------------------------------------------------------------
// Kernel C: final GEMM [2048,2048]x[2048,128] -> f32. grid = (32 i, 4 e-cols).
// ---------------------------------------------------------------------------
__global__ __launch_bounds__(256) void final_kernel(
    const unsigned short* __restrict__ ao,
    const float* __restrict__ last,
    float* __restrict__ outp)
{
    __shared__ __align__(16) unsigned short lt[32 * 68];  // [e_local][k_local]
    const int tid = threadIdx.x;
    const int wave = tid >> 6, lane = tid & 63;
    const int quad = lane >> 4, l16 = lane & 15;
    const int i0 = blockIdx.x * 64;
    const int e0 = blockIdx.y * 32;

    float4v acc[2];
    acc[0] = {0.f, 0.f, 0.f, 0.f};
    acc[1] = {0.f, 0.f, 0.f, 0.f};

    for (int k0 = 0; k0 < HN * DD; k0 += 64) {
        for (int idx2 = tid * 2; idx2 < 64 * 32; idx2 += 512) {
            const int kk = idx2 >> 5, e = idx2 & 31;
            const float2 w2 = *(const float2*)(last + (size_t)(k0 + kk) * DD + e0 + e);
            lt[(e + 0) * 68 + kk] = f2bf(w2.x);
            lt[(e + 1) * 68 + kk] = f2bf(w2.y);
        }
        __syncthreads();
        for (int ks = 0; ks < 2; ks++) {
            const short8 a = *(const short8*)(ao + (size_t)(i0 + wave * 16 + l16) * (HN * DD) + k0 + ks * 32 + quad * 8);
            for (int dc = 0; dc < 2; dc++) {
                const short8 b = ld2x4(&lt[(dc * 16 + l16) * 68 + ks * 32 + quad * 8]);
                acc[dc] = __builtin_amdgcn_mfma_f32_16x16x32_bf16(a, b, acc[dc], 0, 0, 0);
            }
        }
        __syncthreads();
    }
    for (int r = 0; r < 4; r++)
        for (int dc = 0; dc < 2; dc++)
            outp[(size_t)(i0 + wave * 16 + quad * 4 + r) * DD + e0 + dc * 16 + l16] = acc[dc][r];
}

extern "C" void kernel_launch(void* const* d_in, const int* in_sizes, int n_in,
                              void* d_out, int out_size, void* d_ws, size_t ws_size,
                              hipStream_t stream)
{
    const float* q    = (const float*)d_in[0];
    const float* k    = (const float*)d_in[1];
    const float* v    = (const float*)d_in[2];
    const int*   mask = (const int*)d_in[3];
    const float* Qw   = (const float*)d_in[4];
    const float* Kw   = (const float*)d_in[5];
    const float* Vw   = (const float*)d_in[6];
    const float* last = (const float*)d_in[7];
    unsigned short* ws  = (unsigned short*)d_ws;
    float* out = (float*)d_out;

    // ws (bf16): qp[16*2048*128] | kp[...] | vpT[16][128][2048] | ao[2048][2048]
    const size_t needed = (size_t)(3 * HN * NN * DD + NN * HN * DD) * sizeof(unsigned short);
    if (ws_size < needed) {
        sentinel_kernel<<<(out_size + 255) / 256, 256, 0, stream>>>(out, out_size);
        return;
    }

    proj_kernel<<<dim3(32, 16, 3), 256, 0, stream>>>(q, k, v, Qw, Kw, Vw, ws);
    attn_kernel<<<dim3(16, 32), 256, 0, stream>>>(ws, mask);
    final_kernel<<<dim3(32, 4), 256, 0, stream>>>(ws + (size_t)3 * HN * NN * DD, last, out);
}

// Round 9
// 381.286 us; speedup vs baseline: 1.0023x; 1.0023x over previous
//
#include <hip/hip_runtime.h>
#include <hip/hip_bf16.h>

// MultiHeadAttention: N=2048, H=16, D=128. f32 in, f32 out, int32 mask.
// R8->R9: attn was latency-serialized (all pipes <10%): per-iter chain
// qp-load -> S-MFMA -> mask-load -> exp -> LDS -> vpT-load -> PV with zero
// prefetch and only 2 waves/SIMD. Fix: software pipeline in registers
// (VGPR budget 72 -> ~230, still 2 waves/SIMD at <=256):
//   - j-tile 32, two-phase ping-pong loop (no register rotation)
//   - qp B-frags + mask prefetched one full tile ahead
//   - vpT B-frags issued at tile top, consumed at tile bottom
//   - per-phase Pb LDS regions (no WAR wait between tiles)

#define HN 16
#define NN 2048
#define DD 128

typedef __attribute__((ext_vector_type(8))) short short8;   // MFMA A/B frag
typedef __attribute__((ext_vector_type(4))) short short4v;
typedef __attribute__((ext_vector_type(4))) float float4v;  // MFMA C/D frag

__device__ inline unsigned short f2bf(float f) {
    unsigned int u = __builtin_bit_cast(unsigned int, f);
    unsigned int r = (u + 0x7fffu + ((u >> 16) & 1u)) >> 16;  // RNE
    return (unsigned short)r;
}

__device__ inline short8 ld_bf8(const float* __restrict__ p) {
    const float4v a = *(const float4v*)p;
    const float4v b = *(const float4v*)(p + 4);
    short8 r;
    r[0] = (short)f2bf(a[0]); r[1] = (short)f2bf(a[1]);
    r[2] = (short)f2bf(a[2]); r[3] = (short)f2bf(a[3]);
    r[4] = (short)f2bf(b[0]); r[5] = (short)f2bf(b[1]);
    r[6] = (short)f2bf(b[2]); r[7] = (short)f2bf(b[3]);
    return r;
}

__device__ inline short8 ld2x4(const unsigned short* p) {
    const short4v lo = *(const short4v*)p;
    const short4v hi = *(const short4v*)(p + 4);
    short8 r;
    r[0] = lo[0]; r[1] = lo[1]; r[2] = lo[2]; r[3] = lo[3];
    r[4] = hi[0]; r[5] = hi[1]; r[6] = hi[2]; r[7] = hi[3];
    return r;
}

__global__ void sentinel_kernel(float* out, int n) {
    int i = blockIdx.x * 256 + threadIdx.x;
    if (i < n) out[i] = 2.0f;
}

// ---------------------------------------------------------------------------
// Kernel A: projections. grid = (32 row-tiles, 16 heads, 3 tensors).
// t<2: qp/kp row-major [n][d].  t==2: vpT [d][n] via operand swap.
// ---------------------------------------------------------------------------
__global__ __launch_bounds__(256) void proj_kernel(
    const float* __restrict__ q,
    const float* __restrict__ k,
    const float* __restrict__ v,
    const float* __restrict__ Qw,
    const float* __restrict__ Kw,
    const float* __restrict__ Vw,
    unsigned short* __restrict__ ws)
{
    __shared__ __align__(16) unsigned short Wt[128 * 132];  // Wt[e][d] = bf16(W[d][e])
    const int t = blockIdx.z, h = blockIdx.y, rb = blockIdx.x;
    const int tid = threadIdx.x;
    const float* in = (t == 0) ? q : ((t == 1) ? k : v);
    const float* W  = ((t == 0) ? Qw : ((t == 1) ? Kw : Vw)) + h * DD * DD;
    unsigned short* out = ws + (size_t)t * (HN * NN * DD) + (size_t)h * (NN * DD);

    for (int idx2 = tid * 2; idx2 < DD * DD; idx2 += 512) {
        const int d = idx2 >> 7, e = idx2 & 127;
        const float2 w2 = *(const float2*)(W + idx2);
        Wt[(e + 0) * 132 + d] = f2bf(w2.x);
        Wt[(e + 1) * 132 + d] = f2bf(w2.y);
    }
    __syncthreads();

    const int wave = tid >> 6, lane = tid & 63;
    const int quad = lane >> 4, l16 = lane & 15;
    const int row0 = rb * 64 + wave * 16;

    float4v acc[8];
    for (int c = 0; c < 8; c++) acc[c] = {0.f, 0.f, 0.f, 0.f};

    if (t < 2) {
        for (int kk = 0; kk < 4; kk++) {
            const short8 a = ld_bf8(in + (size_t)(row0 + l16) * DD + kk * 32 + quad * 8);
            for (int c = 0; c < 8; c++) {
                const short8 b = ld2x4(&Wt[(c * 16 + l16) * 132 + kk * 32 + quad * 8]);
                acc[c] = __builtin_amdgcn_mfma_f32_16x16x32_bf16(a, b, acc[c], 0, 0, 0);
            }
        }
        for (int c = 0; c < 8; c++)
            for (int r = 0; r < 4; r++)
                out[(size_t)(row0 + quad * 4 + r) * DD + c * 16 + l16] = f2bf(acc[c][r]);
    } else {
        for (int kk = 0; kk < 4; kk++) {
            const short8 bv = ld_bf8(in + (size_t)(row0 + l16) * DD + kk * 32 + quad * 8);
            for (int c = 0; c < 8; c++) {
                const short8 aw = ld2x4(&Wt[(c * 16 + l16) * 132 + kk * 32 + quad * 8]);
                acc[c] = __builtin_amdgcn_mfma_f32_16x16x32_bf16(aw, bv, acc[c], 0, 0, 0);
            }
        }
        for (int c = 0; c < 8; c++)
            for (int r = 0; r < 4; r++)
                out[(size_t)(c * 16 + quad * 4 + r) * NN + row0 + l16] = f2bf(acc[c][r]);
    }
}

// ---------------------------------------------------------------------------
// Kernel B: barrier-free, software-pipelined flash attention.
// grid = (16 heads, 32 i-tiles); j-tile 32, two-phase ping-pong.
// ---------------------------------------------------------------------------
#define PB_PITCH 40   // shorts; l16*40*2 = 80 B, 16B-aligned for b128 reads
__global__ __launch_bounds__(256) void attn_kernel(
    unsigned short* __restrict__ ws,
    const int* __restrict__ mask)
{
    __shared__ __align__(16) unsigned short Pb[2 * 4 * 16 * PB_PITCH];  // phase x wave x 16x32

    const int h = blockIdx.x, ib = blockIdx.y;   // head-major for XCD locality
    const int tid = threadIdx.x;
    const int wave = tid >> 6, lane = tid & 63;
    const int quad = lane >> 4, l16 = lane & 15;

    const unsigned short* qp  = ws + (size_t)h * (NN * DD);
    const unsigned short* kp  = ws + (size_t)(HN * NN * DD) + (size_t)h * (NN * DD);
    const unsigned short* vpT = ws + (size_t)(2 * HN * NN * DD) + (size_t)h * (NN * DD);
    unsigned short* ao = ws + (size_t)(3 * HN * NN * DD);  // [N][H*D]

    const int i0 = ib * 64;
    const float c1 = 0.022097086912079612f * 1.44269504088896f;  // scale*log2e
    const float c2 = -5.0f * 1.44269504088896f;                  // -5*log2e

    short8 ones;
    for (int i = 0; i < 8; i++) ones[i] = (short)0x3F80;  // bf16 1.0

    // kp A-frags (16 i-rows, reused all j-iters)
    short8 afragK[4];
    {
        const int row = i0 + wave * 16 + l16;
        for (int kk = 0; kk < 4; kk++)
            afragK[kk] = *(const short8*)(kp + (size_t)row * DD + kk * 32 + quad * 8);
    }

    unsigned short* Pb0 = &Pb[wave * 16 * PB_PITCH];
    unsigned short* Pb1 = &Pb[(4 + wave) * 16 * PB_PITCH];
    const int gi_base = i0 + wave * 16 + quad * 4;

    float4v o[8];
    for (int c = 0; c < 8; c++) o[c] = {0.f, 0.f, 0.f, 0.f};
    float4v lacc = {0.f, 0.f, 0.f, 0.f};

    // one pipeline stage: compute tile j0C (qp frags/mask already in regs),
    // prefetch qp frags + mask for j0N, vpT frags issued at top of stage.
    auto stage = [&](short8 (&bqC)[8], int (&mvC)[8],
                     short8 (&bqN)[8], int (&mvN)[8],
                     int j0C, int j0N, unsigned short* PbP) {
        // vpT B-frags for current tile: issued first, consumed last
        short8 bv[8];
#pragma unroll
        for (int dc = 0; dc < 8; dc++)
            bv[dc] = *(const short8*)(vpT + (size_t)(dc * 16 + l16) * NN + j0C + quad * 8);
        // prefetch next tile's qp B-frags and mask
#pragma unroll
        for (int kk = 0; kk < 4; kk++)
#pragma unroll
            for (int c = 0; c < 2; c++)
                bqN[kk * 2 + c] = *(const short8*)(qp + (size_t)(j0N + c * 16 + l16) * DD + kk * 32 + quad * 8);
#pragma unroll
        for (int r = 0; r < 4; r++)
#pragma unroll
            for (int c = 0; c < 2; c++)
                mvN[r * 2 + c] = mask[(size_t)(gi_base + r) * NN + j0N + c * 16 + l16];

        // S = kp · qp^T  (16x32 tile of scores)
        float4v s[2];
        s[0] = {0.f, 0.f, 0.f, 0.f};
        s[1] = {0.f, 0.f, 0.f, 0.f};
#pragma unroll
        for (int kk = 0; kk < 4; kk++) {
            s[0] = __builtin_amdgcn_mfma_f32_16x16x32_bf16(afragK[kk], bqC[kk * 2 + 0], s[0], 0, 0, 0);
            s[1] = __builtin_amdgcn_mfma_f32_16x16x32_bf16(afragK[kk], bqC[kk * 2 + 1], s[1], 0, 0, 0);
        }
        // static-max softmax -> Pb (C-layout -> A-layout via per-wave LDS)
#pragma unroll
        for (int r = 0; r < 4; r++)
#pragma unroll
            for (int c = 0; c < 2; c++) {
                const float x = mvC[r * 2 + c] ? fmaf(s[c][r], c1, c2) : -72.0f;
                PbP[(quad * 4 + r) * PB_PITCH + c * 16 + l16] = f2bf(__builtin_amdgcn_exp2f(x));
            }
        const short8 ap = *(const short8*)(&PbP[l16 * PB_PITCH + quad * 8]);
        // O += P · vpT^T ; l += P · 1
#pragma unroll
        for (int dc = 0; dc < 8; dc++)
            o[dc] = __builtin_amdgcn_mfma_f32_16x16x32_bf16(ap, bv[dc], o[dc], 0, 0, 0);
        lacc = __builtin_amdgcn_mfma_f32_16x16x32_bf16(ap, ones, lacc, 0, 0, 0);
    };

    short8 bqA[8], bqB[8];
    int mvA[8], mvB[8];
    // preload tile 0 into A buffers
#pragma unroll
    for (int kk = 0; kk < 4; kk++)
#pragma unroll
        for (int c = 0; c < 2; c++)
            bqA[kk * 2 + c] = *(const short8*)(qp + (size_t)(c * 16 + l16) * DD + kk * 32 + quad * 8);
#pragma unroll
    for (int r = 0; r < 4; r++)
#pragma unroll
        for (int c = 0; c < 2; c++)
            mvA[r * 2 + c] = mask[(size_t)(gi_base + r) * NN + c * 16 + l16];

    for (int j0 = 0; j0 < NN; j0 += 64) {
        const int jb = j0 + 32;
        const int jc = (j0 + 64 < NN) ? (j0 + 64) : 0;  // wrap: dummy in-bounds prefetch
        stage(bqA, mvA, bqB, mvB, j0, jb, Pb0);
        stage(bqB, mvB, bqA, mvA, jb, jc, Pb1);
    }

    // epilogue: normalize, store [i][h*128+d]
    for (int r = 0; r < 4; r++) {
        const float inv = (lacc[r] > 0.f) ? (1.0f / lacc[r]) : 0.f;
        const int gi = gi_base + r;
        for (int dc = 0; dc < 8; dc++)
            ao[(size_t)gi * (HN * DD) + h * DD + dc * 16 + l16] = f2bf(o[dc][r] * inv);
    }
}

// ---------------------------------------------------------------------------
// Kernel C: final GEMM [2048,2048]x[2048,128] -> f32. grid = (32 i, 4 e-cols).
// ---------------------------------------------------------------------------
__global__ __launch_bounds__(256) void final_kernel(
    const unsigned short* __restrict__ ao,
    const float* __restrict__ last,
    float* __restrict__ outp)
{
    __shared__ __align__(16) unsigned short lt[32 * 68];  // [e_local][k_local]
    const int tid = threadIdx.x;
    const int wave = tid >> 6, lane = tid & 63;
    const int quad = lane >> 4, l16 = lane & 15;
    const int i0 = blockIdx.x * 64;
    const int e0 = blockIdx.y * 32;

    float4v acc[2];
    acc[0] = {0.f, 0.f, 0.f, 0.f};
    acc[1] = {0.f, 0.f, 0.f, 0.f};

    for (int k0 = 0; k0 < HN * DD; k0 += 64) {
        for (int idx2 = tid * 2; idx2 < 64 * 32; idx2 += 512) {
            const int kk = idx2 >> 5, e = idx2 & 31;
            const float2 w2 = *(const float2*)(last + (size_t)(k0 + kk) * DD + e0 + e);
            lt[(e + 0) * 68 + kk] = f2bf(w2.x);
            lt[(e + 1) * 68 + kk] = f2bf(w2.y);
        }
        __syncthreads();
        for (int ks = 0; ks < 2; ks++) {
            const short8 a = *(const short8*)(ao + (size_t)(i0 + wave * 16 + l16) * (HN * DD) + k0 + ks * 32 + quad * 8);
            for (int dc = 0; dc < 2; dc++) {
                const short8 b = ld2x4(&lt[(dc * 16 + l16) * 68 + ks * 32 + quad * 8]);
                acc[dc] = __builtin_amdgcn_mfma_f32_16x16x32_bf16(a, b, acc[dc], 0, 0, 0);
            }
        }
        __syncthreads();
    }
    for (int r = 0; r < 4; r++)
        for (int dc = 0; dc < 2; dc++)
            outp[(size_t)(i0 + wave * 16 + quad * 4 + r) * DD + e0 + dc * 16 + l16] = acc[dc][r];
}

extern "C" void kernel_launch(void* const* d_in, const int* in_sizes, int n_in,
                              void* d_out, int out_size, void* d_ws, size_t ws_size,
                              hipStream_t stream)
{
    const float* q    = (const float*)d_in[0];
    const float* k    = (const float*)d_in[1];
    const float* v    = (const float*)d_in[2];
    const int*   mask = (const int*)d_in[3];
    const float* Qw   = (const float*)d_in[4];
    const float* Kw   = (const float*)d_in[5];
    const float* Vw   = (const float*)d_in[6];
    const float* last = (const float*)d_in[7];
    unsigned short* ws  = (unsigned short*)d_ws;
    float* out = (float*)d_out;

    // ws (bf16): qp[16*2048*128] | kp[...] | vpT[16][128][2048] | ao[2048][2048]
    const size_t needed = (size_t)(3 * HN * NN * DD + NN * HN * DD) * sizeof(unsigned short);
    if (ws_size < needed) {
        sentinel_kernel<<<(out_size + 255) / 256, 256, 0, stream>>>(out, out_size);
        return;
    }

    proj_kernel<<<dim3(32, 16, 3), 256, 0, stream>>>(q, k, v, Qw, Kw, Vw, ws);
    attn_kernel<<<dim3(16, 32), 256, 0, stream>>>(ws, mask);
    final_kernel<<<dim3(32, 4), 256, 0, stream>>>(ws + (size_t)3 * HN * NN * DD, last, out);
}